// Round 7
// baseline (89.809 us; speedup 1.0000x reference)
//
#include <hip/hip_runtime.h>
#include <math.h>

// CausalRevIN: B=16, T=8192, C=128, fp32.
// R7: split pass1 into pure single-array sweeps:
//   P1a: mask-only (NT loads, the per-replay COLD stream) -> sumnm + nm-bytes
//   P1b: x-only (L3-warm stream) -> sumx
// so cold misses never serialize warm hits behind them (in-order vmcnt drain),
// and mask never allocates in the MALL. Rest identical to R6 (streaming
// passes, nmb bytes, NT output stores, parallel block scans).
constexpr int B = 16;
constexpr int T = 8192;
constexpr int C = 128;
constexpr int CG = C / 4;      // 32 float4 channel-groups
constexpr int TB = 32;         // t-rows per chunk
constexpr int NC = T / TB;     // 256 chunks per batch == scan blockDim
constexpr int LSUB = TB;       // t-rows per thread in streaming passes
constexpr float STD_MIN = 1e-5f;
constexpr float MAX_VAL = 100.0f;

using f32x4 = __attribute__((ext_vector_type(4))) float;

__device__ inline f32x4 sel_neff(f32x4 n) {
    f32x4 r;
    #pragma unroll
    for (int j = 0; j < 4; ++j) r[j] = (n[j] == 0.0f) ? 1.0f : n[j];
    return r;
}
__device__ inline f32x4 rcp4(f32x4 a) {
    f32x4 r;
    #pragma unroll
    for (int j = 0; j < 4; ++j) r[j] = __builtin_amdgcn_rcpf(a[j]);
    return r;
}
__device__ inline f32x4 sqrt4(f32x4 a) {
    f32x4 r;
    #pragma unroll
    for (int j = 0; j < 4; ++j) r[j] = __builtin_amdgcn_sqrtf(a[j]);
    return r;
}
__device__ inline f32x4 decode_nm(unsigned w) {
    f32x4 r;
    #pragma unroll
    for (int j = 0; j < 4; ++j) r[j] = (float)((w >> (8 * j)) & 0xffu);
    return r;
}

__device__ inline void decomp(int gtid, int& b, int& k, int& cg) {
    cg = gtid & (CG - 1);
    k  = (gtid / CG) & (NC - 1);
    b  = gtid / (CG * NC);
}

// ---------------- P1a: mask-only sweep -> sumnm (+ nm bytes) ---------------
// One block per (b, chunk). Cooperative linear load: flat idx = i*256+tid
// => cg = tid&31 fixed per thread, rows {tid>>5 + 8i} -> private column sums.
template <bool BYTES>
__global__ __launch_bounds__(256) void k_p1a(
    const f32x4* __restrict__ mask, f32x4* __restrict__ sumnm,
    unsigned* __restrict__ nmb)
{
    __shared__ f32x4 p[8][CG];
    int tid = threadIdx.x, cg = tid & 31, sub = tid >> 5;
    int blk = blockIdx.x, b = blk >> 8, kb = blk & 255;
    size_t gbase = (size_t)(b * T + kb * TB) * CG;
    f32x4 sn = {0,0,0,0};
    #pragma unroll
    for (int i = 0; i < 4; ++i) {
        f32x4 mv;
        if (BYTES) mv = __builtin_nontemporal_load(&mask[gbase + i * 256 + tid]);
        else       mv = mask[gbase + i * 256 + tid];
        f32x4 nm = 1.0f - mv;
        if (BYTES) {
            unsigned w = (unsigned)nm[0] | ((unsigned)nm[1] << 8)
                       | ((unsigned)nm[2] << 16) | ((unsigned)nm[3] << 24);
            nmb[gbase + i * 256 + tid] = w;
        }
        sn += nm;
    }
    p[sub][cg] = sn;
    __syncthreads();
    if (sub == 0) {
        f32x4 t = p[0][cg];
        #pragma unroll
        for (int s = 1; s < 8; ++s) t += p[s][cg];
        sumnm[((size_t)b * NC + kb) * CG + cg] = t;
    }
}

// ---------------- P1b: x-only sweep -> sumx --------------------------------
__global__ __launch_bounds__(256) void k_p1b(
    const f32x4* __restrict__ x, f32x4* __restrict__ sumx)
{
    __shared__ f32x4 p[8][CG];
    int tid = threadIdx.x, cg = tid & 31, sub = tid >> 5;
    int blk = blockIdx.x, b = blk >> 8, kb = blk & 255;
    size_t gbase = (size_t)(b * T + kb * TB) * CG;
    f32x4 sx = {0,0,0,0};
    #pragma unroll
    for (int i = 0; i < 4; ++i) sx += x[gbase + i * 256 + tid];
    p[sub][cg] = sx;
    __syncthreads();
    if (sub == 0) {
        f32x4 t = p[0][cg];
        #pragma unroll
        for (int s = 1; s < 8; ++s) t += p[s][cg];
        sumx[((size_t)b * NC + kb) * CG + cg] = t;
    }
}

// ---------------- parallel exclusive block scan over NC=256 ----------------
template <int NCOMP>
__device__ inline void block_exscan(float* vals, int lane, int wave)
{
    float inc[NCOMP];
    #pragma unroll
    for (int j = 0; j < NCOMP; ++j) inc[j] = vals[j];
    #pragma unroll
    for (int d = 1; d < 64; d <<= 1) {
        #pragma unroll
        for (int j = 0; j < NCOMP; ++j) {
            float u = __shfl_up(inc[j], d, 64);
            if (lane >= d) inc[j] += u;
        }
    }
    __shared__ float wsum[4][NCOMP];
    if (lane == 63) {
        #pragma unroll
        for (int j = 0; j < NCOMP; ++j) wsum[wave][j] = inc[j];
    }
    __syncthreads();
    float off[NCOMP];
    #pragma unroll
    for (int j = 0; j < NCOMP; ++j) off[j] = 0.0f;
    for (int w = 0; w < wave; ++w) {
        #pragma unroll
        for (int j = 0; j < NCOMP; ++j) off[j] += wsum[w][j];
    }
    #pragma unroll
    for (int j = 0; j < NCOMP; ++j) {
        float e = __shfl_up(inc[j], 1, 64);
        vals[j] = off[j] + ((lane == 0) ? 0.0f : e);
    }
}

__global__ __launch_bounds__(256) void k_scan2(f32x4* __restrict__ a0,
                                               f32x4* __restrict__ a1)
{
    int blk = blockIdx.x, cg = blk & 31, b = blk >> 5;
    int k = threadIdx.x, lane = k & 63, wave = k >> 6;
    size_t o = ((size_t)b * NC + k) * CG + cg;
    f32x4 v0 = a0[o], v1 = a1[o];
    float vals[8] = {v0[0],v0[1],v0[2],v0[3],v1[0],v1[1],v1[2],v1[3]};
    block_exscan<8>(vals, lane, wave);
    a0[o] = (f32x4){vals[0],vals[1],vals[2],vals[3]};
    a1[o] = (f32x4){vals[4],vals[5],vals[6],vals[7]};
}

__global__ __launch_bounds__(256) void k_scan1(f32x4* __restrict__ a0)
{
    int blk = blockIdx.x, cg = blk & 31, b = blk >> 5;
    int k = threadIdx.x, lane = k & 63, wave = k >> 6;
    size_t o = ((size_t)b * NC + k) * CG + cg;
    f32x4 v0 = a0[o];
    float vals[4] = {v0[0],v0[1],v0[2],v0[3]};
    block_exscan<4>(vals, lane, wave);
    a0[o] = (f32x4){vals[0],vals[1],vals[2],vals[3]};
}

// ---------------- P3: per-chunk dev^2 sums ---------------------------------
template <bool BYTES>
__global__ __launch_bounds__(256) void k_pass3(
    const f32x4* __restrict__ x, const f32x4* __restrict__ mask,
    const unsigned* __restrict__ nmb,
    const f32x4* __restrict__ psumx, const f32x4* __restrict__ psumnm,
    f32x4* __restrict__ sumd2)
{
    int gtid = blockIdx.x * 256 + threadIdx.x;
    int b, k, cg; decomp(gtid, b, k, cg);
    size_t base = ((size_t)b * T + (size_t)k * LSUB) * CG + cg;
    size_t o = ((size_t)b * NC + k) * CG + cg;
    f32x4 rx = psumx[o], rn = psumnm[o];
    f32x4 sd = {0,0,0,0};
    #pragma unroll 8
    for (int t = 0; t < LSUB; ++t) {
        f32x4 xv = x[base + (size_t)t * CG];
        f32x4 nm = BYTES ? decode_nm(nmb[base + (size_t)t * CG])
                         : (1.0f - mask[base + (size_t)t * CG]);
        rx += xv; rn += nm;
        f32x4 mean = rx * rcp4(sel_neff(rn));
        f32x4 d = (xv - mean) * nm;
        sd += d * d;
    }
    sumd2[o] = sd;
}

// ---------------- P5: final normalize + clip (single sweep, NT out) --------
template <bool BYTES>
__global__ __launch_bounds__(256) void k_pass5(
    const f32x4* __restrict__ x, const f32x4* __restrict__ mask,
    const unsigned* __restrict__ nmb,
    const f32x4* __restrict__ psumx, const f32x4* __restrict__ psumnm,
    const f32x4* __restrict__ psumd2, f32x4* __restrict__ out)
{
    int gtid = blockIdx.x * 256 + threadIdx.x;
    int b, k, cg; decomp(gtid, b, k, cg);
    size_t base = ((size_t)b * T + (size_t)k * LSUB) * CG + cg;
    size_t o = ((size_t)b * NC + k) * CG + cg;
    f32x4 rx = psumx[o], rn = psumnm[o], rd = psumd2[o];
    #pragma unroll 8
    for (int t = 0; t < LSUB; ++t) {
        f32x4 xv = x[base + (size_t)t * CG];
        f32x4 nm = BYTES ? decode_nm(nmb[base + (size_t)t * CG])
                         : (1.0f - mask[base + (size_t)t * CG]);
        rx += xv; rn += nm;
        f32x4 inv = rcp4(sel_neff(rn));
        f32x4 mean = rx * inv;
        f32x4 d = (xv - mean) * nm;
        rd += d * d;
        f32x4 s = sqrt4(rd * inv);
        f32x4 ov;
        #pragma unroll
        for (int j = 0; j < 4; ++j) {
            float invs = (s[j] > STD_MIN) ? __builtin_amdgcn_rcpf(s[j]) : 1.0f;
            float v = (xv[j] - mean[j]) * invs;
            ov[j] = fminf(fmaxf(v, -MAX_VAL), MAX_VAL);
        }
        __builtin_nontemporal_store(ov, &out[base + (size_t)t * CG]);
    }
}

template <bool BYTES>
static void run_all(const f32x4* x, const f32x4* mask, f32x4* out,
                    void* d_ws, hipStream_t stream)
{
    size_t arr_elems = (size_t)B * NC * C;   // floats per scan array
    f32x4* sumx  = (f32x4*)d_ws;
    f32x4* sumnm = (f32x4*)((float*)d_ws + arr_elems);
    f32x4* sumd2 = (f32x4*)((float*)d_ws + 2 * arr_elems);
    unsigned* nmb = (unsigned*)((float*)d_ws + 3 * arr_elems);

    int tile_blocks = B * NC;             // 4096 (one per (b,chunk))
    int main_blocks = B * NC * CG / 256;  // 512
    int scan_blocks = B * CG;             // 512

    k_p1b<<<tile_blocks, 256, 0, stream>>>(x, sumx);
    k_p1a<BYTES><<<tile_blocks, 256, 0, stream>>>(mask, sumnm, nmb);
    k_scan2<<<scan_blocks, 256, 0, stream>>>(sumx, sumnm);
    k_pass3<BYTES><<<main_blocks, 256, 0, stream>>>(x, mask, nmb, sumx, sumnm, sumd2);
    k_scan1<<<scan_blocks, 256, 0, stream>>>(sumd2);
    k_pass5<BYTES><<<main_blocks, 256, 0, stream>>>(x, mask, nmb, sumx, sumnm, sumd2, out);
}

extern "C" void kernel_launch(void* const* d_in, const int* in_sizes, int n_in,
                              void* d_out, int out_size, void* d_ws, size_t ws_size,
                              hipStream_t stream) {
    const f32x4* x    = (const f32x4*)d_in[0];
    const f32x4* mask = (const f32x4*)d_in[1];
    f32x4* out = (f32x4*)d_out;

    size_t need = 3ull * B * NC * C * sizeof(float)      // 6 MiB scan arrays
                + (size_t)B * T * CG * sizeof(unsigned); // 16 MiB nm bytes

    if (ws_size >= need) run_all<true >(x, mask, out, d_ws, stream);
    else                 run_all<false>(x, mask, out, d_ws, stream);
}